// Round 1
// baseline (12627.962 us; speedup 1.0000x reference)
//
#include <hip/hip_runtime.h>
#include <hip/hip_bf16.h>

// Stacked 2-layer Elman RNN, B=2048 T=256 H=512 OUT=1.
// Strategy: batch-parallel blocks (BM=16 rows/block, 128 blocks), h0/h1 state
// lives in LDS (fp16, XOR-swizzled) across all 256 steps. Per step each block
// streams Wh0/Wx1/Wh1 (pre-converted fp16, MFMA-fragment layout in d_ws) from
// L2 and runs mfma_f32_16x16x32_f16 with fp32 accumulators.

typedef _Float16 half8 __attribute__((ext_vector_type(8)));
typedef float f32x4 __attribute__((ext_vector_type(4)));

#define T_STEPS 256
#define H_DIM   512
#define BM      16   // batch rows per block

// fast tanh: sign(z) * (1-e)/(1+e), e = exp(-2|z|).  err ~1e-6, monotone-safe.
__device__ __forceinline__ float tanh_fast(float z){
  float az = fabsf(z);
  float e  = __expf(-2.0f * az);
  float r  = (1.0f - e) * __builtin_amdgcn_rcpf(1.0f + e);
  return copysignf(r, z);
}

// Convert one 512x512 fp32 matrix (stored [k][n], i.e. (in,out)) into fp16
// MFMA-B fragments: out[((nt*16+kc)*64+lane)] = 8 halves, where
//   col = nt*16 + (lane&15),  k = kc*32 + (lane>>4)*8 + j
__global__ void prep_w_45028437131357(const float* __restrict__ W,
                                      half8* __restrict__ out){
  int tid  = blockIdx.x * 256 + threadIdx.x;   // 0..32767
  int lane = tid & 63;
  int kc   = (tid >> 6) & 15;
  int nt   = tid >> 10;                        // 0..31
  int col  = nt * 16 + (lane & 15);
  int k0   = kc * 32 + (lane >> 4) * 8;
  half8 v;
#pragma unroll
  for (int j = 0; j < 8; ++j) v[j] = (_Float16)W[(k0 + j) * H_DIM + col];
  out[tid] = v;
}

// LDS h layout: element (row, c) at byte  row*1024 + ((c*2) ^ ((row&7)<<4))
// (XOR swizzle keeps ds_read_b128 A-frag fetches ~2-way, i.e. free).

__global__ __launch_bounds__(512, 2)
void rnn_main_45028437131357(const float* __restrict__ x,
                             const float* __restrict__ Wx0,
                             const float* __restrict__ bx0,
                             const float* __restrict__ bh0,
                             const float* __restrict__ bx1,
                             const float* __restrict__ bh1,
                             const float* __restrict__ Wfc,
                             const float* __restrict__ bfc,
                             const half8* __restrict__ Wh0f,
                             const half8* __restrict__ Wx1f,
                             const half8* __restrict__ Wh1f,
                             float* __restrict__ out){
  __shared__ __align__(16) char h0raw[BM * 1024];
  __shared__ __align__(16) char h1raw[BM * 1024];
  __shared__ float xl[BM];

  const int tid  = threadIdx.x;
  const int lane = tid & 63;
  const int wave = tid >> 6;            // 0..7, owns n-tiles {wave+8*i}
  const int r0   = blockIdx.x * BM;

  // zero initial hidden state
  for (int i = tid; i < BM * 1024 / 4; i += 512){
    ((float*)h0raw)[i] = 0.0f;
    ((float*)h1raw)[i] = 0.0f;
  }

  const int cl      = lane & 15;        // A row / C-D col within tile
  const int kg      = lane >> 4;        // 0..3
  const int aBase   = cl * 1024 + kg * 16;  // + kc*64, then ^aSwz
  const int aSwz    = (cl & 7) << 4;
  const int rowBase = kg * 4;           // C/D rows = rowBase + reg

  // per-tile column constants (cols = (wave+8*i)*16 + cl)
  float wx0c[4], b0c[4], b1c[4];
  int   colT[4];
#pragma unroll
  for (int i = 0; i < 4; ++i){
    int col  = (wave + 8 * i) * 16 + cl;
    colT[i]  = col;
    wx0c[i]  = Wx0[col];
    b0c[i]   = bx0[col] + bh0[col];
    b1c[i]   = bx1[col] + bh1[col];
  }

  float xreg = 0.0f;
  if (tid < BM) xreg = x[(r0 + tid) * T_STEPS];   // prefetch t=0

  const f32x4 z4 = {0.f, 0.f, 0.f, 0.f};

  for (int t = 0; t < T_STEPS; ++t){
    if (tid < BM) xl[tid] = xreg;
    __syncthreads();                              // B1: xl + prev h1 visible
    // prefetch next step's x column (latency hides under this step)
    {
      int tn = (t + 1 < T_STEPS) ? t + 1 : t;
      if (tid < BM) xreg = x[(r0 + tid) * T_STEPS + tn];
    }

    // ---------- layer 0: z0 = h0 @ Wh0 ----------
    f32x4 acc0[4] = {z4, z4, z4, z4};
#pragma unroll
    for (int kc = 0; kc < 16; ++kc){
      half8 a = *(const half8*)(h0raw + ((aBase + kc * 64) ^ aSwz));
#pragma unroll
      for (int i = 0; i < 4; ++i){
        half8 b = Wh0f[((wave + 8 * i) * 16 + kc) * 64 + lane];
        acc0[i] = __builtin_amdgcn_mfma_f32_16x16x32_f16(a, b, acc0[i], 0, 0, 0);
      }
    }
    float xv[4];
#pragma unroll
    for (int rg = 0; rg < 4; ++rg) xv[rg] = xl[rowBase + rg];
    _Float16 nh0[4][4];
#pragma unroll
    for (int i = 0; i < 4; ++i)
#pragma unroll
      for (int rg = 0; rg < 4; ++rg){
        float z = acc0[i][rg] + b0c[i] + xv[rg] * wx0c[i];
        nh0[i][rg] = (_Float16)tanh_fast(z);
      }
    __syncthreads();                              // B2: all h0 reads done
#pragma unroll
    for (int i = 0; i < 4; ++i)
#pragma unroll
      for (int rg = 0; rg < 4; ++rg){
        int row = rowBase + rg;
        *(_Float16*)(h0raw + row * 1024 + ((colT[i] * 2) ^ ((row & 7) << 4))) =
            nh0[i][rg];
      }
    __syncthreads();                              // B3: new h0 visible

    // ---------- layer 1: z1 = h0_new @ Wx1 + h1 @ Wh1 ----------
    f32x4 acc1[4] = {z4, z4, z4, z4};
#pragma unroll
    for (int kc = 0; kc < 16; ++kc){
      half8 a = *(const half8*)(h0raw + ((aBase + kc * 64) ^ aSwz));
#pragma unroll
      for (int i = 0; i < 4; ++i){
        half8 b = Wx1f[((wave + 8 * i) * 16 + kc) * 64 + lane];
        acc1[i] = __builtin_amdgcn_mfma_f32_16x16x32_f16(a, b, acc1[i], 0, 0, 0);
      }
    }
#pragma unroll
    for (int kc = 0; kc < 16; ++kc){
      half8 a = *(const half8*)(h1raw + ((aBase + kc * 64) ^ aSwz));
#pragma unroll
      for (int i = 0; i < 4; ++i){
        half8 b = Wh1f[((wave + 8 * i) * 16 + kc) * 64 + lane];
        acc1[i] = __builtin_amdgcn_mfma_f32_16x16x32_f16(a, b, acc1[i], 0, 0, 0);
      }
    }
    _Float16 nh1[4][4];
#pragma unroll
    for (int i = 0; i < 4; ++i)
#pragma unroll
      for (int rg = 0; rg < 4; ++rg){
        float z = acc1[i][rg] + b1c[i];
        nh1[i][rg] = (_Float16)tanh_fast(z);
      }
    __syncthreads();                              // B4: all h1 reads done
#pragma unroll
    for (int i = 0; i < 4; ++i)
#pragma unroll
      for (int rg = 0; rg < 4; ++rg){
        int row = rowBase + rg;
        *(_Float16*)(h1raw + row * 1024 + ((colT[i] * 2) ^ ((row & 7) << 4))) =
            nh1[i][rg];
      }
    // next iteration's B1 makes h1_new visible before any L1 read
  }
  __syncthreads();

  // ---------- final FC: out[r] = h1[r,:] . Wfc + bfc ----------
  int r = tid >> 5;        // 0..15
  int g = tid & 31;
  float p = 0.0f;
#pragma unroll
  for (int k2 = 0; k2 < 16; ++k2){
    int c = g + 32 * k2;
    float hv = (float)*(const _Float16*)(h1raw + r * 1024 +
                                         ((c * 2) ^ ((r & 7) << 4)));
    p += hv * Wfc[c];
  }
#pragma unroll
  for (int off = 16; off >= 1; off >>= 1) p += __shfl_xor(p, off);
  if (g == 0) out[r0 + r] = p + bfc[0];
}

extern "C" void kernel_launch(void* const* d_in, const int* in_sizes, int n_in,
                              void* d_out, int out_size, void* d_ws, size_t ws_size,
                              hipStream_t stream) {
  const float* x   = (const float*)d_in[0];
  const float* Wx0 = (const float*)d_in[1];
  const float* bx0 = (const float*)d_in[2];
  const float* Wh0 = (const float*)d_in[3];
  const float* bh0 = (const float*)d_in[4];
  const float* Wx1 = (const float*)d_in[5];
  const float* bx1 = (const float*)d_in[6];
  const float* Wh1 = (const float*)d_in[7];
  const float* bh1 = (const float*)d_in[8];
  const float* Wfc = (const float*)d_in[9];
  const float* bfc = (const float*)d_in[10];

  _Float16* wsH = (_Float16*)d_ws;                 // 3 x 512x512 fp16 = 1.5 MB
  half8* Wh0f = (half8*)(wsH);
  half8* Wx1f = (half8*)(wsH + 262144);
  half8* Wh1f = (half8*)(wsH + 524288);

  prep_w_45028437131357<<<128, 256, 0, stream>>>(Wh0, Wh0f);
  prep_w_45028437131357<<<128, 256, 0, stream>>>(Wx1, Wx1f);
  prep_w_45028437131357<<<128, 256, 0, stream>>>(Wh1, Wh1f);

  rnn_main_45028437131357<<<128, 512, 0, stream>>>(
      x, Wx0, bx0, bh0, bx1, bh1, Wfc, bfc,
      (const half8*)Wh0f, (const half8*)Wx1f, (const half8*)Wh1f,
      (float*)d_out);
}

// Round 2
// 10965.662 us; speedup vs baseline: 1.1516x; 1.1516x over previous
//
#include <hip/hip_runtime.h>
#include <hip/hip_bf16.h>

// Stacked 2-layer Elman RNN, B=2048 T=256 H=512 OUT=1.
// Weight-stationary persistent RNN: 128 blocks x 16 waves; the 3 weight
// matrices (fp16, MFMA-B fragment layout) live in VGPRs, distributed across
// the 16 waves of each block with zero replication (384 VGPR/wave).
// Per step only the h-state (16KB) moves through LDS.
//   waves 0-7  ("L0"): Wh0 strips, n-tiles 4g..4g+3   (256 VGPR)
//   waves 8-15 ("L1"): Wh1 strips, n-tiles 4g..4g+3   (256 VGPR)
//   all waves:         Wx1 strips, n-tiles 2w..2w+1   (128 VGPR)
// Step: [A] L0: acc=h0@Wh0 || L1: pacc=h1@Wh1 -> LDS; L0 writes h0_new.
//       barrier. [B] all: acc2 = pacc + h0_new@Wx1 -> h1_new. barrier(top).

typedef _Float16 half8 __attribute__((ext_vector_type(8)));
typedef float f32x4 __attribute__((ext_vector_type(4)));

#define T_STEPS 256
#define H_DIM   512
#define BM      16

__device__ __forceinline__ float tanh_fast(float z){
  float az = fabsf(z);
  float e  = __expf(-2.0f * az);
  float r  = (1.0f - e) * __builtin_amdgcn_rcpf(1.0f + e);
  return copysignf(r, z);
}

// fp32 [k][n] -> fp16 MFMA-B fragments: out[(nt*16+kc)*64+lane] = 8 halves,
// col = nt*16 + (lane&15), k = kc*32 + (lane>>4)*8 + j
__global__ void prep_w_45028437131357(const float* __restrict__ W,
                                      half8* __restrict__ out){
  int tid  = blockIdx.x * 256 + threadIdx.x;
  int lane = tid & 63;
  int kc   = (tid >> 6) & 15;
  int nt   = tid >> 10;
  int col  = nt * 16 + (lane & 15);
  int k0   = kc * 32 + (lane >> 4) * 8;
  half8 v;
#pragma unroll
  for (int j = 0; j < 8; ++j) v[j] = (_Float16)W[(k0 + j) * H_DIM + col];
  out[tid] = v;
}

// LDS h layout: element (row, c) at byte  row*1024 + ((c*2) ^ ((row&7)<<4))

__global__ __launch_bounds__(1024, 1)
void rnn_main_45028437131357(const float* __restrict__ x,
                             const float* __restrict__ Wx0,
                             const float* __restrict__ bx0,
                             const float* __restrict__ bh0,
                             const float* __restrict__ bx1,
                             const float* __restrict__ bh1,
                             const float* __restrict__ Wfc,
                             const float* __restrict__ bfc,
                             const half8* __restrict__ Wh0f,
                             const half8* __restrict__ Wx1f,
                             const half8* __restrict__ Wh1f,
                             float* __restrict__ out){
  __shared__ __align__(16) char  h0raw[2][BM * 1024];
  __shared__ __align__(16) char  h1raw[BM * 1024];
  __shared__ __align__(16) float pacc[32 * 64 * 4];   // [tile][lane][4] f32
  __shared__ float xl[BM];

  const int tid  = threadIdx.x;
  const int lane = tid & 63;
  const int wave = tid >> 6;          // 0..15
  const int g    = wave & 7;
  const bool isL0 = (wave < 8);
  const int r0   = blockIdx.x * BM;

  // zero initial hidden state (h0 both buffers + h1)
  for (int i = tid; i < 2 * BM * 256; i += 1024) ((float*)h0raw)[i] = 0.0f;
  for (int i = tid; i < BM * 256;     i += 1024) ((float*)h1raw)[i] = 0.0f;

  // ---- persistent weights -> VGPRs (once) ----
  const half8* wAsrc = isL0 ? Wh0f : Wh1f;
  half8 wA[4][16];
#pragma unroll
  for (int i = 0; i < 4; ++i)
#pragma unroll
    for (int kc = 0; kc < 16; ++kc)
      wA[i][kc] = wAsrc[((4 * g + i) * 16 + kc) * 64 + lane];
  half8 wX[2][16];
#pragma unroll
  for (int i = 0; i < 2; ++i)
#pragma unroll
    for (int kc = 0; kc < 16; ++kc)
      wX[i][kc] = Wx1f[((2 * wave + i) * 16 + kc) * 64 + lane];

  const int cl      = lane & 15;
  const int kg      = lane >> 4;
  const int aBase   = cl * 1024 + kg * 16;
  const int aSwz    = (cl & 7) << 4;
  const int rowBase = kg * 4;

  // per-column constants
  float wx0c[4], b0c[4];
  int   colA[4];
#pragma unroll
  for (int i = 0; i < 4; ++i){
    int col = (4 * g + i) * 16 + cl;
    colA[i] = col;
    wx0c[i] = Wx0[col];
    b0c[i]  = bx0[col] + bh0[col];
  }
  float b1c[2];
  int   colX[2];
#pragma unroll
  for (int i = 0; i < 2; ++i){
    int col = (2 * wave + i) * 16 + cl;
    colX[i] = col;
    b1c[i]  = bx1[col] + bh1[col];
  }

  float xreg = 0.0f;
  if (tid < BM) xreg = x[(r0 + tid) * T_STEPS];

  const f32x4 z4 = {0.f, 0.f, 0.f, 0.f};
  int s = 0;

  for (int t = 0; t < T_STEPS; ++t){
    if (tid < BM) xl[tid] = xreg;
    __syncthreads();                          // B0: h1_new(t-1), xl visible
    {
      int tn = (t + 1 < T_STEPS) ? t + 1 : t;
      if (tid < BM) xreg = x[(r0 + tid) * T_STEPS + tn];
    }

    // ---- phase A: L0: h0_old@Wh0 ; L1: h1_old@Wh1 ----
    const char* aBuf = isL0 ? h0raw[s] : h1raw;
    f32x4 accA[4] = {z4, z4, z4, z4};
#pragma unroll
    for (int kc = 0; kc < 16; ++kc){
      half8 a = *(const half8*)(aBuf + ((aBase + kc * 64) ^ aSwz));
#pragma unroll
      for (int i = 0; i < 4; ++i)
        accA[i] = __builtin_amdgcn_mfma_f32_16x16x32_f16(a, wA[i][kc], accA[i], 0, 0, 0);
    }

    if (isL0){
      float xv[4];
#pragma unroll
      for (int rg = 0; rg < 4; ++rg) xv[rg] = xl[rowBase + rg];
#pragma unroll
      for (int i = 0; i < 4; ++i)
#pragma unroll
        for (int rg = 0; rg < 4; ++rg){
          float z = accA[i][rg] + b0c[i] + xv[rg] * wx0c[i];
          int row = rowBase + rg;
          *(_Float16*)(h0raw[s ^ 1] + row * 1024 +
                       ((colA[i] * 2) ^ ((row & 7) << 4))) = (_Float16)tanh_fast(z);
        }
    } else {
#pragma unroll
      for (int i = 0; i < 4; ++i)
        *(f32x4*)(pacc + ((4 * g + i) * 64 + lane) * 4) = accA[i];
    }
    __syncthreads();                          // B1: h0_new + pacc visible

    // ---- phase B: all waves: acc2 = pacc + h0_new@Wx1 ----
    f32x4 acc2[2];
#pragma unroll
    for (int i = 0; i < 2; ++i)
      acc2[i] = *(const f32x4*)(pacc + ((2 * wave + i) * 64 + lane) * 4);
#pragma unroll
    for (int kc = 0; kc < 16; ++kc){
      half8 a = *(const half8*)(h0raw[s ^ 1] + ((aBase + kc * 64) ^ aSwz));
#pragma unroll
      for (int i = 0; i < 2; ++i)
        acc2[i] = __builtin_amdgcn_mfma_f32_16x16x32_f16(a, wX[i][kc], acc2[i], 0, 0, 0);
    }
#pragma unroll
    for (int i = 0; i < 2; ++i)
#pragma unroll
      for (int rg = 0; rg < 4; ++rg){
        float z = acc2[i][rg] + b1c[i];
        int row = rowBase + rg;
        *(_Float16*)(h1raw + row * 1024 +
                     ((colX[i] * 2) ^ ((row & 7) << 4))) = (_Float16)tanh_fast(z);
      }
    s ^= 1;
  }
  __syncthreads();

  // ---- final FC: out[r] = h1[r,:] . Wfc + bfc ----
  if (tid < 512){
    int r  = tid >> 5;
    int g2 = tid & 31;
    float p = 0.0f;
#pragma unroll
    for (int k2 = 0; k2 < 16; ++k2){
      int c = g2 + 32 * k2;
      float hv = (float)*(const _Float16*)(h1raw + r * 1024 +
                                           ((c * 2) ^ ((r & 7) << 4)));
      p += hv * Wfc[c];
    }
#pragma unroll
    for (int off = 16; off >= 1; off >>= 1) p += __shfl_xor(p, off);
    if (g2 == 0) out[r0 + r] = p + bfc[0];
  }
}

extern "C" void kernel_launch(void* const* d_in, const int* in_sizes, int n_in,
                              void* d_out, int out_size, void* d_ws, size_t ws_size,
                              hipStream_t stream) {
  const float* x   = (const float*)d_in[0];
  const float* Wx0 = (const float*)d_in[1];
  const float* bx0 = (const float*)d_in[2];
  const float* Wh0 = (const float*)d_in[3];
  const float* bh0 = (const float*)d_in[4];
  const float* Wx1 = (const float*)d_in[5];
  const float* bx1 = (const float*)d_in[6];
  const float* Wh1 = (const float*)d_in[7];
  const float* bh1 = (const float*)d_in[8];
  const float* Wfc = (const float*)d_in[9];
  const float* bfc = (const float*)d_in[10];

  _Float16* wsH = (_Float16*)d_ws;
  half8* Wh0f = (half8*)(wsH);
  half8* Wx1f = (half8*)(wsH + 262144);
  half8* Wh1f = (half8*)(wsH + 524288);

  prep_w_45028437131357<<<128, 256, 0, stream>>>(Wh0, Wh0f);
  prep_w_45028437131357<<<128, 256, 0, stream>>>(Wx1, Wx1f);
  prep_w_45028437131357<<<128, 256, 0, stream>>>(Wh1, Wh1f);

  rnn_main_45028437131357<<<128, 1024, 0, stream>>>(
      x, Wx0, bx0, bh0, bx1, bh1, Wfc, bfc,
      (const half8*)Wh0f, (const half8*)Wx1f, (const half8*)Wh1f,
      (float*)d_out);
}